// Round 12
// baseline (106.658 us; speedup 1.0000x reference)
//
#include <hip/hip_runtime.h>
#include <hip/hip_bf16.h>

// MultiHeadAttention: B=4,S=2048,E=1024,H=16,D=64. Q=K=V=x@Wq^T (quirk),
// causal, scale 1/32 (sqrt(OUT_DIM) quirk). fp32 in/out, bf16 MFMA compute.
// ws: [0,16MiB) q bf16 [B,H,S,D]; [16MiB,32MiB) qT bf16 [B,H,D,S].
// r12 = attn reverted to r7 exactly (best measured: 53.3us);
//       qproj BK=64 + DEPTH-2 register prefetch (full-step latency cover).

using bf16 = __hip_bfloat16;
typedef __attribute__((ext_vector_type(8))) short bf16x8;
typedef __attribute__((ext_vector_type(4))) float f32x4;
typedef __attribute__((ext_vector_type(16))) float f32x16;
typedef __attribute__((ext_vector_type(2))) unsigned int u32x2;

#define MFMA16(a, b, c) __builtin_amdgcn_mfma_f32_16x16x32_bf16((a), (b), (c), 0, 0, 0)
#define MFMA32(a, b, c) __builtin_amdgcn_mfma_f32_32x32x16_bf16((a), (b), (c), 0, 0, 0)

// hardware packed f32x2 -> bf16x2 (RNE), T12 recipe
static __device__ __forceinline__ unsigned cvtpk(float lo, float hi) {
  unsigned r;
  asm("v_cvt_pk_bf16_f32 %0, %1, %2" : "=v"(r) : "v"(lo), "v"(hi));
  return r;
}
// scale a bf16x8 fragment by s (unpack, mul, repack)
static __device__ __forceinline__ bf16x8 scale8(bf16x8 f, float s) {
  union { bf16x8 v; unsigned w[4]; } u, r;
  u.v = f;
#pragma unroll
  for (int i = 0; i < 4; ++i) {
    float lo = __uint_as_float(u.w[i] << 16) * s;
    float hi = __uint_as_float(u.w[i] & 0xffff0000u) * s;
    r.w[i] = cvtpk(lo, hi);
  }
  return r.v;
}

// ---------------------------------------------------------------------------
// Kernel 1: q = x @ Wq^T (M=8192,N=1024,K=1024). 128x128 tile, 4 waves, BK=64.
// r12: depth-2 prefetch — loads for slab s+2 issue while slab s computes and
// slab s+1 (loaded a full step ago) is written to LDS. Two named reg sets,
// unrolled-by-2 steady state. Epilogue (LDS-transpose qT) unchanged from r7.
// ---------------------------------------------------------------------------
__global__ __launch_bounds__(256, 2) void qproj_kernel(
    const float* __restrict__ x, const float* __restrict__ w,
    ushort* __restrict__ q, ushort* __restrict__ qT) {
  __shared__ union {
    struct { ushort As[2][128][72]; ushort Bs[2][128][72]; } ab;  // 73.7KB
    ushort Tt[128][138];  // [dh-local][s-local] transpose tile, 276B stride
  } sm;
  const int tid = threadIdx.x;
  const int wid = tid >> 6, lane = tid & 63;
  const int l16 = lane & 15, lhi = lane >> 4;
  const int wrow = wid >> 1, wcol = wid & 1;
  const int m0 = blockIdx.x * 128, n0 = blockIdx.y * 128;

  // staging coords: 8 chunks/matrix, row_i = 16*i + (tid>>4), col = (tid&15)*4
  const int srow = tid >> 4, scol = (tid & 15) * 4;

  f32x4 acc[4][4] = {};
  float4 xa0[8], wb0[8], xa1[8], wb1[8];

  auto load_slab = [&](float4* xa, float4* wb, int k0) {
#pragma unroll
    for (int i = 0; i < 8; ++i) {
      xa[i] = *reinterpret_cast<const float4*>(&x[(m0 + srow + 16 * i) * 1024 + k0 + scol]);
      wb[i] = *reinterpret_cast<const float4*>(&w[(n0 + srow + 16 * i) * 1024 + k0 + scol]);
    }
  };
  auto write_slab = [&](int buf, const float4* xa, const float4* wb) {
#pragma unroll
    for (int i = 0; i < 8; ++i) {
      uint2 pa = {cvtpk(xa[i].x, xa[i].y), cvtpk(xa[i].z, xa[i].w)};
      uint2 pb = {cvtpk(wb[i].x, wb[i].y), cvtpk(wb[i].z, wb[i].w)};
      *reinterpret_cast<uint2*>(&sm.ab.As[buf][srow + 16 * i][scol]) = pa;
      *reinterpret_cast<uint2*>(&sm.ab.Bs[buf][srow + 16 * i][scol]) = pb;
    }
  };
  auto mfma_slab = [&](int buf) {
    __builtin_amdgcn_s_setprio(1);
#pragma unroll
    for (int kk = 0; kk < 64; kk += 32) {
      bf16x8 af[4], bfr[4];
#pragma unroll
      for (int mr = 0; mr < 4; ++mr)
        af[mr] = *reinterpret_cast<const bf16x8*>(&sm.ab.As[buf][wrow * 64 + mr * 16 + l16][kk + lhi * 8]);
#pragma unroll
      for (int nr = 0; nr < 4; ++nr)
        bfr[nr] = *reinterpret_cast<const bf16x8*>(&sm.ab.Bs[buf][wcol * 64 + nr * 16 + l16][kk + lhi * 8]);
#pragma unroll
      for (int mr = 0; mr < 4; ++mr)
#pragma unroll
        for (int nr = 0; nr < 4; ++nr)
          acc[mr][nr] = MFMA16(af[mr], bfr[nr], acc[mr][nr]);
    }
    __builtin_amdgcn_s_setprio(0);
  };

  // prologue: slab0 -> buf0 (written); slab1 in flight in set1
  load_slab(xa0, wb0, 0);
  write_slab(0, xa0, wb0);
  load_slab(xa1, wb1, 64);
  __syncthreads();

  // steady state: 16 slabs, unrolled by 2. Invariants at even substep s:
  //   buf0 holds slab s (ready); set1 holds slab s+1 (arrived); issue s+2.
#pragma unroll 1
  for (int s = 0; s < 16; s += 2) {
    if (s + 2 < 16) load_slab(xa0, wb0, (s + 2) * 64);
    mfma_slab(0);
    if (s + 1 < 16) write_slab(1, xa1, wb1);
    __syncthreads();

    if (s + 3 < 16) load_slab(xa1, wb1, (s + 3) * 64);
    mfma_slab(1);
    if (s + 2 < 16) write_slab(0, xa0, wb0);
    __syncthreads();
  }

  // epilogue: As/Bs dead; reuse LDS as transpose tile (r7)
#pragma unroll
  for (int mr = 0; mr < 4; ++mr)
#pragma unroll
    for (int nr = 0; nr < 4; ++nr) {
      unsigned w01 = cvtpk(acc[mr][nr][0], acc[mr][nr][1]);
      unsigned w23 = cvtpk(acc[mr][nr][2], acc[mr][nr][3]);
      int rloc = wrow * 64 + mr * 16 + lhi * 4;
      int cloc = wcol * 64 + nr * 16 + l16;
      int gr = m0 + rloc, gc = n0 + cloc;
      int bb = gr >> 11, hh = gc >> 6, dh = gc & 63;
      ushort* qp = &q[(((bb * 16 + hh) * 2048) + (gr & 2047)) * 64 + dh];
      qp[0] = (ushort)(w01 & 0xffffu);
      qp[64] = (ushort)(w01 >> 16);
      qp[128] = (ushort)(w23 & 0xffffu);
      qp[192] = (ushort)(w23 >> 16);
      *reinterpret_cast<unsigned*>(&sm.Tt[cloc][rloc]) = w01;
      *reinterpret_cast<unsigned*>(&sm.Tt[cloc][rloc + 2]) = w23;
    }
  __syncthreads();

  const int bb = m0 >> 11, sl = m0 & 2047;
#pragma unroll
  for (int pp = 0; pp < 2; ++pp) {
    int dh_loc = (tid >> 2) + pp * 64;
    int gc = n0 + dh_loc;
    int hh = gc >> 6, dh = gc & 63;
    ushort* base = &qT[(((bb * 16 + hh) * 64) + dh) * 2048 + sl];
#pragma unroll
    for (int k = 0; k < 4; ++k) {
      int sb = (tid & 3) * 8 + k * 32;
      bf16x8 v = *reinterpret_cast<const bf16x8*>(&sm.Tt[dh_loc][sb]);
      *reinterpret_cast<bf16x8*>(&base[sb]) = v;
    }
  }
}

// ---------------------------------------------------------------------------
// Kernel 2: causal flash attention, K=V=Q. EXACT r7 version (measured 53.3us,
// 92 VGPR): 512 blocks x 4 waves, 128-row q-tiles, qt-pairing (i,15-i),
// KVBLK=128 double-buffered, T14 reg prefetch, fixed-m softmax, pre-scaled Q,
// hw cvt_pk + permlane32_swap. (r8/r11 re-schedules measured negative.)
// ---------------------------------------------------------------------------
__global__ __launch_bounds__(256, 2) void attn_kernel(
    const ushort* __restrict__ q, const ushort* __restrict__ qT,
    float* __restrict__ out) {
  __shared__ ushort Ks[2][128][72];    // [buf][key][d]  144B stride: conflict-free
  __shared__ ushort VTs[2][64][136];   // [buf][d][key]  272B stride: conflict-free
  const int tid = threadIdx.x, wid = tid >> 6, lane = tid & 63;
  const int l31 = lane & 31, h = lane >> 5;
  const int bid = blockIdx.x;
  const int pi = bid >> 6, bh = bid & 63;
  const int qtA = pi, qtB = 15 - pi;   // 128-row q tiles
  const int ntA = pi + 1;              // 128-key tiles for item A
  const int T = 17;                    // ntA + ntB == 17 for every block
  const ushort* Q = q + bh * (2048 * 64);
  const ushort* VT = qT + bh * (64 * 2048);
  float* O = out + (bh >> 4) * (2048 * 1024) + (bh & 15) * 64;

  int qw = qtA * 128 + wid * 32;
  int qglob = qw + l31;

  const int krow = tid >> 3, kc8 = (tid & 7) * 8;    // K: 4 rows/thread (+32)
  const int vrow = tid >> 4, vc8 = (tid & 15) * 8;   // VT: 4 rows/thread (+16)

  const float sc = 0.03125f * 1.44269504f;  // 1/sqrt(1024) * log2(e)

  bf16x8 qb[4];
#pragma unroll
  for (int ds = 0; ds < 4; ++ds)
    qb[ds] = scale8(*reinterpret_cast<const bf16x8*>(&Q[qglob * 64 + ds * 16 + h * 8]), sc);

  f32x16 o0 = {}, o1 = {};             // O^T[d][q]
  float l_run = 0.f;

  auto store_out = [&]() {
    float lt = l_run + __shfl_xor(l_run, 32);
    float inv = 1.0f / lt;
#pragma unroll
    for (int rq = 0; rq < 4; ++rq) {
      float4 v0, v1;
      v0.x = o0[4 * rq + 0] * inv; v0.y = o0[4 * rq + 1] * inv;
      v0.z = o0[4 * rq + 2] * inv; v0.w = o0[4 * rq + 3] * inv;
      v1.x = o1[4 * rq + 0] * inv; v1.y = o1[4 * rq + 1] * inv;
      v1.z = o1[4 * rq + 2] * inv; v1.w = o1[4 * rq + 3] * inv;
      *reinterpret_cast<float4*>(&O[qglob * 1024 + 8 * rq + 4 * h]) = v0;
      *reinterpret_cast<float4*>(&O[qglob * 1024 + 32 + 8 * rq + 4 * h]) = v1;
    }
  };

  bf16x8 kr[4], vr[4];
  // prologue: stage tile kv=0 into buffer 0
#pragma unroll
  for (int i = 0; i < 4; ++i) {
    kr[i] = *reinterpret_cast<const bf16x8*>(&Q[(krow + 32 * i) * 64 + kc8]);
    vr[i] = *reinterpret_cast<const bf16x8*>(&VT[(vrow + 16 * i) * 2048 + vc8]);
    *reinterpret_cast<bf16x8*>(&Ks[0][krow + 32 * i][kc8]) = kr[i];
    *reinterpret_cast<bf16x8*>(&VTs[0][vrow + 16 * i][vc8]) = vr[i];
  }
  __syncthreads();

  for (int t = 0; t < T; ++t) {
    const int p = t & 1;
    const bool more = (t + 1 < T);

    if (t == ntA) {  // item switch: finish A, start B
      store_out();
      o0 = {}; o1 = {};
      l_run = 0.f;
      qw = qtB * 128 + wid * 32;
      qglob = qw + l31;
#pragma unroll
      for (int ds = 0; ds < 4; ++ds)
        qb[ds] = scale8(*reinterpret_cast<const bf16x8*>(&Q[qglob * 64 + ds * 16 + h * 8]), sc);
    }
    const int kv0 = (t < ntA) ? t * 128 : (t - ntA) * 128;
    const bool diag = (t == ntA - 1) || (t == T - 1);  // item's last tile

    if (more) {  // issue next-tile global loads early (T14); kv wraps at ntA
      const int nkv = (t + 1 < ntA) ? (t + 1) * 128 : (t + 1 - ntA) * 128;
#pragma unroll
      for (int i = 0; i < 4; ++i) {
        kr[i] = *reinterpret_cast<const bf16x8*>(&Q[(nkv + krow + 32 * i) * 64 + kc8]);
        vr[i] = *reinterpret_cast<const bf16x8*>(&VT[(vrow + 16 * i) * 2048 + nkv + vc8]);
      }
    }

    // S^T*sc = K (Q*sc)^T: 4 chains x 4 k-steps. D: col=q=lane&31, row=key.
    f32x16 st[4] = {{}, {}, {}, {}};
    __builtin_amdgcn_s_setprio(1);
#pragma unroll
    for (int ds = 0; ds < 4; ++ds) {
#pragma unroll
      for (int c = 0; c < 4; ++c) {
        bf16x8 ka = *reinterpret_cast<const bf16x8*>(&Ks[p][32 * c + l31][ds * 16 + h * 8]);
        st[c] = MFMA32(ka, qb[ds], st[c]);
      }
    }
    __builtin_amdgcn_s_setprio(0);

    if (diag) {  // causal mask, only on the item's last tile
#pragma unroll
      for (int c = 0; c < 4; ++c)
#pragma unroll
        for (int r = 0; r < 16; ++r) {
          int key = kv0 + 32 * c + (r & 3) + 8 * (r >> 2) + 4 * h;
          if (key > qglob) st[c][r] = -1e30f;
        }
    }

    // fixed-m softmax: p = exp2(st) (scale pre-folded into Q)
    float ls = 0.f;
#pragma unroll
    for (int c = 0; c < 4; ++c)
#pragma unroll
      for (int r = 0; r < 16; ++r) {
        float pv = __builtin_amdgcn_exp2f(st[c][r]);
        st[c][r] = pv;
        ls += pv;
      }
    l_run += ls;

    // O^T += V^T P^T: 8 key-steps of 16; hw pack + 2 permlane32_swap each.
    __builtin_amdgcn_s_setprio(1);
#pragma unroll
    for (int ks = 0; ks < 8; ++ks) {
      const int cc = ks >> 1, b8 = (ks & 1) * 8;
      unsigned a0 = cvtpk(st[cc][b8 + 0], st[cc][b8 + 1]);
      unsigned a1 = cvtpk(st[cc][b8 + 2], st[cc][b8 + 3]);
      unsigned b0 = cvtpk(st[cc][b8 + 4], st[cc][b8 + 5]);
      unsigned b1 = cvtpk(st[cc][b8 + 6], st[cc][b8 + 7]);
      u32x2 r0 = __builtin_amdgcn_permlane32_swap(a0, b0, false, false);
      u32x2 r1 = __builtin_amdgcn_permlane32_swap(a1, b1, false, false);
      union { unsigned w[4]; bf16x8 v; } pb;
      pb.w[0] = r0.x; pb.w[1] = r1.x; pb.w[2] = r0.y; pb.w[3] = r1.y;
      bf16x8 va0 = *reinterpret_cast<const bf16x8*>(&VTs[p][l31][ks * 16 + h * 8]);
      bf16x8 va1 = *reinterpret_cast<const bf16x8*>(&VTs[p][32 + l31][ks * 16 + h * 8]);
      o0 = MFMA32(va0, pb.v, o0);
      o1 = MFMA32(va1, pb.v, o1);
    }
    __builtin_amdgcn_s_setprio(0);

    if (more) {  // write next tile into the other buffer
#pragma unroll
      for (int i = 0; i < 4; ++i) {
        *reinterpret_cast<bf16x8*>(&Ks[p ^ 1][krow + 32 * i][kc8]) = kr[i];
        *reinterpret_cast<bf16x8*>(&VTs[p ^ 1][vrow + 16 * i][vc8]) = vr[i];
      }
      __syncthreads();
    }
  }

  store_out();  // item B epilogue
}

extern "C" void kernel_launch(void* const* d_in, const int* in_sizes, int n_in,
                              void* d_out, int out_size, void* d_ws, size_t ws_size,
                              hipStream_t stream) {
  const float* x = (const float*)d_in[0];
  const float* w = (const float*)d_in[1];
  float* out = (float*)d_out;
  ushort* qb = (ushort*)d_ws;
  ushort* qTb = qb + 4 * 16 * 2048 * 64;
  qproj_kernel<<<dim3(64, 8), 256, 0, stream>>>(x, w, qb, qTb);
  attn_kernel<<<512, 256, 0, stream>>>(qb, qTb, out);
}

// Round 13
// 89.476 us; speedup vs baseline: 1.1920x; 1.1920x over previous
//
#include <hip/hip_runtime.h>
#include <hip/hip_bf16.h>

// MultiHeadAttention: B=4,S=2048,E=1024,H=16,D=64. Q=K=V=x@Wq^T (quirk),
// causal, scale 1/32 (sqrt(OUT_DIM) quirk). fp32 in/out, bf16 MFMA compute.
// ws: [0,16MiB) q bf16 [B,H,S,D]; [16MiB,32MiB) qT bf16 [B,H,D,S].
// r13 = attn r7 exact (53.3us, proven 4x) + qproj re-tiled 128x64 for
//       4 blocks/CU (grid was the occupancy limiter; r12's depth-2 spilled).

using bf16 = __hip_bfloat16;
typedef __attribute__((ext_vector_type(8))) short bf16x8;
typedef __attribute__((ext_vector_type(4))) float f32x4;
typedef __attribute__((ext_vector_type(16))) float f32x16;
typedef __attribute__((ext_vector_type(2))) unsigned int u32x2;

#define MFMA16(a, b, c) __builtin_amdgcn_mfma_f32_16x16x32_bf16((a), (b), (c), 0, 0, 0)
#define MFMA32(a, b, c) __builtin_amdgcn_mfma_f32_32x32x16_bf16((a), (b), (c), 0, 0, 0)

// hardware packed f32x2 -> bf16x2 (RNE), T12 recipe
static __device__ __forceinline__ unsigned cvtpk(float lo, float hi) {
  unsigned r;
  asm("v_cvt_pk_bf16_f32 %0, %1, %2" : "=v"(r) : "v"(lo), "v"(hi));
  return r;
}
// scale a bf16x8 fragment by s (unpack, mul, repack)
static __device__ __forceinline__ bf16x8 scale8(bf16x8 f, float s) {
  union { bf16x8 v; unsigned w[4]; } u, r;
  u.v = f;
#pragma unroll
  for (int i = 0; i < 4; ++i) {
    float lo = __uint_as_float(u.w[i] << 16) * s;
    float hi = __uint_as_float(u.w[i] & 0xffff0000u) * s;
    r.w[i] = cvtpk(lo, hi);
  }
  return r.v;
}

// ---------------------------------------------------------------------------
// Kernel 1: q = x @ Wq^T (M=8192,N=1024,K=1024). r13: 128x64 tile, 4 waves
// (each wave owns 32 M-rows x all 64 N-cols), BK=32, depth-1 reg prefetch,
// double-buffered LDS (30KB) -> grid 1024 = 4 blocks/CU (TLP doubled).
// Epilogue: direct q store + LDS-transpose for coalesced qT (r7 scheme).
// ---------------------------------------------------------------------------
__global__ __launch_bounds__(256, 4) void qproj_kernel(
    const float* __restrict__ x, const float* __restrict__ w,
    ushort* __restrict__ q, ushort* __restrict__ qT) {
  __shared__ union {
    struct { ushort As[2][128][40]; ushort Bs[2][64][40]; } ab;  // 30KB
    ushort Tt[64][138];  // [dh-local][s-local] transpose tile, 276B stride
  } sm;
  const int tid = threadIdx.x;
  const int wid = tid >> 6, lane = tid & 63;
  const int l16 = lane & 15, lhi = lane >> 4;
  const int m0 = blockIdx.x * 128, n0 = blockIdx.y * 64;

  // staging coords: A 4 chunks (row (e>>5), col e&31), B 2 chunks
  const int bre = tid >> 3, bce = (tid & 7) * 4;   // B rows 0..31 (+32), cols 0..28

  f32x4 acc[2][4] = {};
  float4 xa[4], wb[2];

  auto load_slab = [&](int k0) {
#pragma unroll
    for (int i = 0; i < 4; ++i) {
      int e = (i * 256 + tid) * 4;
      xa[i] = *reinterpret_cast<const float4*>(&x[(m0 + (e >> 5)) * 1024 + k0 + (e & 31)]);
    }
#pragma unroll
    for (int i = 0; i < 2; ++i)
      wb[i] = *reinterpret_cast<const float4*>(&w[(n0 + bre + 32 * i) * 1024 + k0 + bce]);
  };
  auto write_slab = [&](int buf) {
#pragma unroll
    for (int i = 0; i < 4; ++i) {
      int e = (i * 256 + tid) * 4;
      uint2 pa = {cvtpk(xa[i].x, xa[i].y), cvtpk(xa[i].z, xa[i].w)};
      *reinterpret_cast<uint2*>(&sm.ab.As[buf][e >> 5][e & 31]) = pa;
    }
#pragma unroll
    for (int i = 0; i < 2; ++i) {
      uint2 pb = {cvtpk(wb[i].x, wb[i].y), cvtpk(wb[i].z, wb[i].w)};
      *reinterpret_cast<uint2*>(&sm.ab.Bs[buf][bre + 32 * i][bce]) = pb;
    }
  };

  // prologue
  load_slab(0);
  write_slab(0);
  __syncthreads();

  for (int k0 = 0; k0 < 1024; k0 += 32) {
    const int p = (k0 >> 5) & 1;
    const bool more = (k0 + 32 < 1024);
    if (more) load_slab(k0 + 32);  // depth-1 reg prefetch (T14)

    bf16x8 af[2], bfr[4];
#pragma unroll
    for (int mr = 0; mr < 2; ++mr)
      af[mr] = *reinterpret_cast<const bf16x8*>(&sm.ab.As[p][wid * 32 + mr * 16 + l16][lhi * 8]);
#pragma unroll
    for (int nr = 0; nr < 4; ++nr)
      bfr[nr] = *reinterpret_cast<const bf16x8*>(&sm.ab.Bs[p][nr * 16 + l16][lhi * 8]);
    __builtin_amdgcn_s_setprio(1);
#pragma unroll
    for (int mr = 0; mr < 2; ++mr)
#pragma unroll
      for (int nr = 0; nr < 4; ++nr)
        acc[mr][nr] = MFMA16(af[mr], bfr[nr], acc[mr][nr]);
    __builtin_amdgcn_s_setprio(0);

    if (more) {
      write_slab(p ^ 1);
      __syncthreads();
    }
  }

  __syncthreads();  // As/Bs dead; reuse LDS as transpose tile

  const int hh = n0 >> 6;  // whole 64-col tile lies in one head
#pragma unroll
  for (int mr = 0; mr < 2; ++mr)
#pragma unroll
    for (int nr = 0; nr < 4; ++nr) {
      unsigned w01 = cvtpk(acc[mr][nr][0], acc[mr][nr][1]);
      unsigned w23 = cvtpk(acc[mr][nr][2], acc[mr][nr][3]);
      int rloc = wid * 32 + mr * 16 + lhi * 4;   // s-local (j base, 4-aligned)
      int dh = nr * 16 + l16;                    // dh-local = dh (single head)
      int gr = m0 + rloc;
      int bb = gr >> 11;
      // direct q store: 16 lanes x 2B = 32B sector-aligned groups
      ushort* qp = &q[(((bb * 16 + hh) * 2048) + (gr & 2047)) * 64 + dh];
      qp[0] = (ushort)(w01 & 0xffffu);
      qp[64] = (ushort)(w01 >> 16);
      qp[128] = (ushort)(w23 & 0xffffu);
      qp[192] = (ushort)(w23 >> 16);
      // transpose tile write (b32 pairs along s)
      *reinterpret_cast<unsigned*>(&sm.Tt[dh][rloc]) = w01;
      *reinterpret_cast<unsigned*>(&sm.Tt[dh][rloc + 2]) = w23;
    }
  __syncthreads();

  // coalesced qT stores: 4 lanes cover 64B contiguous in s per instr.
  const int bb = m0 >> 11, sl = m0 & 2047;
  {
    int dh = tid >> 2;  // 0..63
    ushort* base = &qT[(((bb * 16 + hh) * 64) + dh) * 2048 + sl];
#pragma unroll
    for (int k = 0; k < 4; ++k) {
      int sb = (tid & 3) * 8 + k * 32;  // s-local element offset
      bf16x8 v = *reinterpret_cast<const bf16x8*>(&sm.Tt[dh][sb]);
      *reinterpret_cast<bf16x8*>(&base[sb]) = v;
    }
  }
}

// ---------------------------------------------------------------------------
// Kernel 2: causal flash attention, K=V=Q. EXACT r7 version (measured 53.3us,
// 92 VGPR): 512 blocks x 4 waves, 128-row q-tiles, qt-pairing (i,15-i),
// KVBLK=128 double-buffered, T14 reg prefetch, fixed-m softmax, pre-scaled Q,
// hw cvt_pk + permlane32_swap. (r8/r9/r10/r11 restructures all regressed.)
// ---------------------------------------------------------------------------
__global__ __launch_bounds__(256, 2) void attn_kernel(
    const ushort* __restrict__ q, const ushort* __restrict__ qT,
    float* __restrict__ out) {
  __shared__ ushort Ks[2][128][72];    // [buf][key][d]  144B stride: conflict-free
  __shared__ ushort VTs[2][64][136];   // [buf][d][key]  272B stride: conflict-free
  const int tid = threadIdx.x, wid = tid >> 6, lane = tid & 63;
  const int l31 = lane & 31, h = lane >> 5;
  const int bid = blockIdx.x;
  const int pi = bid >> 6, bh = bid & 63;
  const int qtA = pi, qtB = 15 - pi;   // 128-row q tiles
  const int ntA = pi + 1;              // 128-key tiles for item A
  const int T = 17;                    // ntA + ntB == 17 for every block
  const ushort* Q = q + bh * (2048 * 64);
  const ushort* VT = qT + bh * (64 * 2048);
  float* O = out + (bh >> 4) * (2048 * 1024) + (bh & 15) * 64;

  int qw = qtA * 128 + wid * 32;
  int qglob = qw + l31;

  const int krow = tid >> 3, kc8 = (tid & 7) * 8;    // K: 4 rows/thread (+32)
  const int vrow = tid >> 4, vc8 = (tid & 15) * 8;   // VT: 4 rows/thread (+16)

  const float sc = 0.03125f * 1.44269504f;  // 1/sqrt(1024) * log2(e)

  bf16x8 qb[4];
#pragma unroll
  for (int ds = 0; ds < 4; ++ds)
    qb[ds] = scale8(*reinterpret_cast<const bf16x8*>(&Q[qglob * 64 + ds * 16 + h * 8]), sc);

  f32x16 o0 = {}, o1 = {};             // O^T[d][q]
  float l_run = 0.f;

  auto store_out = [&]() {
    float lt = l_run + __shfl_xor(l_run, 32);
    float inv = 1.0f / lt;
#pragma unroll
    for (int rq = 0; rq < 4; ++rq) {
      float4 v0, v1;
      v0.x = o0[4 * rq + 0] * inv; v0.y = o0[4 * rq + 1] * inv;
      v0.z = o0[4 * rq + 2] * inv; v0.w = o0[4 * rq + 3] * inv;
      v1.x = o1[4 * rq + 0] * inv; v1.y = o1[4 * rq + 1] * inv;
      v1.z = o1[4 * rq + 2] * inv; v1.w = o1[4 * rq + 3] * inv;
      *reinterpret_cast<float4*>(&O[qglob * 1024 + 8 * rq + 4 * h]) = v0;
      *reinterpret_cast<float4*>(&O[qglob * 1024 + 32 + 8 * rq + 4 * h]) = v1;
    }
  };

  bf16x8 kr[4], vr[4];
  // prologue: stage tile kv=0 into buffer 0
#pragma unroll
  for (int i = 0; i < 4; ++i) {
    kr[i] = *reinterpret_cast<const bf16x8*>(&Q[(krow + 32 * i) * 64 + kc8]);
    vr[i] = *reinterpret_cast<const bf16x8*>(&VT[(vrow + 16 * i) * 2048 + vc8]);
    *reinterpret_cast<bf16x8*>(&Ks[0][krow + 32 * i][kc8]) = kr[i];
    *reinterpret_cast<bf16x8*>(&VTs[0][vrow + 16 * i][vc8]) = vr[i];
  }
  __syncthreads();

  for (int t = 0; t < T; ++t) {
    const int p = t & 1;
    const bool more = (t + 1 < T);

    if (t == ntA) {  // item switch: finish A, start B
      store_out();
      o0 = {}; o1 = {};
      l_run = 0.f;
      qw = qtB * 128 + wid * 32;
      qglob = qw + l31;
#pragma unroll
      for (int ds = 0; ds < 4; ++ds)
        qb[ds] = scale8(*reinterpret_cast<const bf16x8*>(&Q[qglob * 64 + ds * 16 + h * 8]), sc);
    }
    const int kv0 = (t < ntA) ? t * 128 : (t - ntA) * 128;
    const bool diag = (t == ntA - 1) || (t == T - 1);  // item's last tile

    if (more) {  // issue next-tile global loads early (T14); kv wraps at ntA
      const int nkv = (t + 1 < ntA) ? (t + 1) * 128 : (t + 1 - ntA) * 128;
#pragma unroll
      for (int i = 0; i < 4; ++i) {
        kr[i] = *reinterpret_cast<const bf16x8*>(&Q[(nkv + krow + 32 * i) * 64 + kc8]);
        vr[i] = *reinterpret_cast<const bf16x8*>(&VT[(vrow + 16 * i) * 2048 + nkv + vc8]);
      }
    }

    // S^T*sc = K (Q*sc)^T: 4 chains x 4 k-steps. D: col=q=lane&31, row=key.
    f32x16 st[4] = {{}, {}, {}, {}};
    __builtin_amdgcn_s_setprio(1);
#pragma unroll
    for (int ds = 0; ds < 4; ++ds) {
#pragma unroll
      for (int c = 0; c < 4; ++c) {
        bf16x8 ka = *reinterpret_cast<const bf16x8*>(&Ks[p][32 * c + l31][ds * 16 + h * 8]);
        st[c] = MFMA32(ka, qb[ds], st[c]);
      }
    }
    __builtin_amdgcn_s_setprio(0);

    if (diag) {  // causal mask, only on the item's last tile
#pragma unroll
      for (int c = 0; c < 4; ++c)
#pragma unroll
        for (int r = 0; r < 16; ++r) {
          int key = kv0 + 32 * c + (r & 3) + 8 * (r >> 2) + 4 * h;
          if (key > qglob) st[c][r] = -1e30f;
        }
    }

    // fixed-m softmax: p = exp2(st) (scale pre-folded into Q)
    float ls = 0.f;
#pragma unroll
    for (int c = 0; c < 4; ++c)
#pragma unroll
      for (int r = 0; r < 16; ++r) {
        float pv = __builtin_amdgcn_exp2f(st[c][r]);
        st[c][r] = pv;
        ls += pv;
      }
    l_run += ls;

    // O^T += V^T P^T: 8 key-steps of 16; hw pack + 2 permlane32_swap each.
    __builtin_amdgcn_s_setprio(1);
#pragma unroll
    for (int ks = 0; ks < 8; ++ks) {
      const int cc = ks >> 1, b8 = (ks & 1) * 8;
      unsigned a0 = cvtpk(st[cc][b8 + 0], st[cc][b8 + 1]);
      unsigned a1 = cvtpk(st[cc][b8 + 2], st[cc][b8 + 3]);
      unsigned b0 = cvtpk(st[cc][b8 + 4], st[cc][b8 + 5]);
      unsigned b1 = cvtpk(st[cc][b8 + 6], st[cc][b8 + 7]);
      u32x2 r0 = __builtin_amdgcn_permlane32_swap(a0, b0, false, false);
      u32x2 r1 = __builtin_amdgcn_permlane32_swap(a1, b1, false, false);
      union { unsigned w[4]; bf16x8 v; } pb;
      pb.w[0] = r0.x; pb.w[1] = r1.x; pb.w[2] = r0.y; pb.w[3] = r1.y;
      bf16x8 va0 = *reinterpret_cast<const bf16x8*>(&VTs[p][l31][ks * 16 + h * 8]);
      bf16x8 va1 = *reinterpret_cast<const bf16x8*>(&VTs[p][32 + l31][ks * 16 + h * 8]);
      o0 = MFMA32(va0, pb.v, o0);
      o1 = MFMA32(va1, pb.v, o1);
    }
    __builtin_amdgcn_s_setprio(0);

    if (more) {  // write next tile into the other buffer
#pragma unroll
      for (int i = 0; i < 4; ++i) {
        *reinterpret_cast<bf16x8*>(&Ks[p ^ 1][krow + 32 * i][kc8]) = kr[i];
        *reinterpret_cast<bf16x8*>(&VTs[p ^ 1][vrow + 16 * i][vc8]) = vr[i];
      }
      __syncthreads();
    }
  }

  store_out();  // item B epilogue
}

extern "C" void kernel_launch(void* const* d_in, const int* in_sizes, int n_in,
                              void* d_out, int out_size, void* d_ws, size_t ws_size,
                              hipStream_t stream) {
  const float* x = (const float*)d_in[0];
  const float* w = (const float*)d_in[1];
  float* out = (float*)d_out;
  ushort* qb = (ushort*)d_ws;
  ushort* qTb = qb + 4 * 16 * 2048 * 64;
  qproj_kernel<<<dim3(64, 16), 256, 0, stream>>>(x, w, qb, qTb);
  attn_kernel<<<512, 256, 0, stream>>>(qb, qTb, out);
}

// Round 14
// 83.691 us; speedup vs baseline: 1.2744x; 1.0691x over previous
//
#include <hip/hip_runtime.h>
#include <hip/hip_bf16.h>

// MultiHeadAttention: B=4,S=2048,E=1024,H=16,D=64. Q=K=V=x@Wq^T (quirk),
// causal, scale 1/32 (sqrt(OUT_DIM) quirk). fp32 in/out, bf16 MFMA compute.
// ws: [0,16MiB) q bf16 [B,H,S,D]; [16MiB,32MiB) qT bf16 [B,H,D,S].
// r14 = CONSOLIDATION of best-measured components:
//   qproj: r11 version (128x128, BK=64, [72] stride, depth-1 prefetch) ~27us
//   attn:  r7 version (512x4waves, KVBLK=128, qt-pairing) 53.3us
// (r8-r13 restructures of either kernel all measured worse.)

using bf16 = __hip_bfloat16;
typedef __attribute__((ext_vector_type(8))) short bf16x8;
typedef __attribute__((ext_vector_type(4))) float f32x4;
typedef __attribute__((ext_vector_type(16))) float f32x16;
typedef __attribute__((ext_vector_type(2))) unsigned int u32x2;

#define MFMA16(a, b, c) __builtin_amdgcn_mfma_f32_16x16x32_bf16((a), (b), (c), 0, 0, 0)
#define MFMA32(a, b, c) __builtin_amdgcn_mfma_f32_32x32x16_bf16((a), (b), (c), 0, 0, 0)

// hardware packed f32x2 -> bf16x2 (RNE), T12 recipe
static __device__ __forceinline__ unsigned cvtpk(float lo, float hi) {
  unsigned r;
  asm("v_cvt_pk_bf16_f32 %0, %1, %2" : "=v"(r) : "v"(lo), "v"(hi));
  return r;
}
// scale a bf16x8 fragment by s (unpack, mul, repack)
static __device__ __forceinline__ bf16x8 scale8(bf16x8 f, float s) {
  union { bf16x8 v; unsigned w[4]; } u, r;
  u.v = f;
#pragma unroll
  for (int i = 0; i < 4; ++i) {
    float lo = __uint_as_float(u.w[i] << 16) * s;
    float hi = __uint_as_float(u.w[i] & 0xffff0000u) * s;
    r.w[i] = cvtpk(lo, hi);
  }
  return r.v;
}

// ---------------------------------------------------------------------------
// Kernel 1: q = x @ Wq^T (M=8192,N=1024,K=1024). 128x128 tile, 4 waves, BK=64
// (r11): depth-1 reg prefetch, hw cvtpk staging, one barrier per K-slab,
// LDS-transpose epilogue with odd-stride pad for coalesced qT stores.
// ---------------------------------------------------------------------------
__global__ __launch_bounds__(256, 2) void qproj_kernel(
    const float* __restrict__ x, const float* __restrict__ w,
    ushort* __restrict__ q, ushort* __restrict__ qT) {
  __shared__ union {
    struct { ushort As[2][128][72]; ushort Bs[2][128][72]; } ab;  // 73.7KB
    ushort Tt[128][138];  // [dh-local][s-local] transpose tile, 276B stride
  } sm;
  const int tid = threadIdx.x;
  const int wid = tid >> 6, lane = tid & 63;
  const int l16 = lane & 15, lhi = lane >> 4;
  const int wrow = wid >> 1, wcol = wid & 1;
  const int m0 = blockIdx.x * 128, n0 = blockIdx.y * 128;

  // staging coords: 8 chunks/matrix, row_i = 16*i + (tid>>4), col = (tid&15)*4
  const int srow = tid >> 4, scol = (tid & 15) * 4;

  f32x4 acc[4][4] = {};
  float4 xa[8], wb[8];

  // prologue: load k0=0 slab, convert, write buffer 0
#pragma unroll
  for (int i = 0; i < 8; ++i) {
    xa[i] = *reinterpret_cast<const float4*>(&x[(m0 + srow + 16 * i) * 1024 + scol]);
    wb[i] = *reinterpret_cast<const float4*>(&w[(n0 + srow + 16 * i) * 1024 + scol]);
  }
#pragma unroll
  for (int i = 0; i < 8; ++i) {
    uint2 pa = {cvtpk(xa[i].x, xa[i].y), cvtpk(xa[i].z, xa[i].w)};
    uint2 pb = {cvtpk(wb[i].x, wb[i].y), cvtpk(wb[i].z, wb[i].w)};
    *reinterpret_cast<uint2*>(&sm.ab.As[0][srow + 16 * i][scol]) = pa;
    *reinterpret_cast<uint2*>(&sm.ab.Bs[0][srow + 16 * i][scol]) = pb;
  }
  __syncthreads();

  for (int k0 = 0; k0 < 1024; k0 += 64) {
    const int p = (k0 >> 6) & 1;
    const bool more = (k0 + 64 < 1024);
    if (more) {  // prefetch next K-slab into regs (T14, depth-1)
#pragma unroll
      for (int i = 0; i < 8; ++i) {
        xa[i] = *reinterpret_cast<const float4*>(&x[(m0 + srow + 16 * i) * 1024 + k0 + 64 + scol]);
        wb[i] = *reinterpret_cast<const float4*>(&w[(n0 + srow + 16 * i) * 1024 + k0 + 64 + scol]);
      }
    }

    __builtin_amdgcn_s_setprio(1);
#pragma unroll
    for (int kk = 0; kk < 64; kk += 32) {
      bf16x8 af[4], bfr[4];
#pragma unroll
      for (int mr = 0; mr < 4; ++mr)
        af[mr] = *reinterpret_cast<const bf16x8*>(&sm.ab.As[p][wrow * 64 + mr * 16 + l16][kk + lhi * 8]);
#pragma unroll
      for (int nr = 0; nr < 4; ++nr)
        bfr[nr] = *reinterpret_cast<const bf16x8*>(&sm.ab.Bs[p][wcol * 64 + nr * 16 + l16][kk + lhi * 8]);
#pragma unroll
      for (int mr = 0; mr < 4; ++mr)
#pragma unroll
        for (int nr = 0; nr < 4; ++nr)
          acc[mr][nr] = MFMA16(af[mr], bfr[nr], acc[mr][nr]);
    }
    __builtin_amdgcn_s_setprio(0);

    if (more) {  // convert + write the other buffer, one barrier per slab
#pragma unroll
      for (int i = 0; i < 8; ++i) {
        uint2 pa = {cvtpk(xa[i].x, xa[i].y), cvtpk(xa[i].z, xa[i].w)};
        uint2 pb = {cvtpk(wb[i].x, wb[i].y), cvtpk(wb[i].z, wb[i].w)};
        *reinterpret_cast<uint2*>(&sm.ab.As[p ^ 1][srow + 16 * i][scol]) = pa;
        *reinterpret_cast<uint2*>(&sm.ab.Bs[p ^ 1][srow + 16 * i][scol]) = pb;
      }
      __syncthreads();
    }
  }

  __syncthreads();  // As/Bs dead; reuse LDS as transpose tile

#pragma unroll
  for (int mr = 0; mr < 4; ++mr)
#pragma unroll
    for (int nr = 0; nr < 4; ++nr) {
      unsigned w01 = cvtpk(acc[mr][nr][0], acc[mr][nr][1]);
      unsigned w23 = cvtpk(acc[mr][nr][2], acc[mr][nr][3]);
      int rloc = wrow * 64 + mr * 16 + lhi * 4;   // s-local (j base, 4-aligned)
      int cloc = wcol * 64 + nr * 16 + l16;       // dh-local
      int gr = m0 + rloc, gc = n0 + cloc;
      int bb = gr >> 11, hh = gc >> 6, dh = gc & 63;
      // direct q store: 16 lanes x 2B = 32B sector-aligned groups
      ushort* qp = &q[(((bb * 16 + hh) * 2048) + (gr & 2047)) * 64 + dh];
      qp[0] = (ushort)(w01 & 0xffffu);
      qp[64] = (ushort)(w01 >> 16);
      qp[128] = (ushort)(w23 & 0xffffu);
      qp[192] = (ushort)(w23 >> 16);
      // transpose tile write (b32 pairs along s); odd dword stride -> clean
      *reinterpret_cast<unsigned*>(&sm.Tt[cloc][rloc]) = w01;
      *reinterpret_cast<unsigned*>(&sm.Tt[cloc][rloc + 2]) = w23;
    }
  __syncthreads();

  // coalesced qT stores: per instr, 4 lanes cover 64B contiguous in s.
  const int bb = m0 >> 11, sl = m0 & 2047;
#pragma unroll
  for (int pp = 0; pp < 2; ++pp) {
    int dh_loc = (tid >> 2) + pp * 64;
    int gc = n0 + dh_loc;
    int hh = gc >> 6, dh = gc & 63;
    ushort* base = &qT[(((bb * 16 + hh) * 64) + dh) * 2048 + sl];
#pragma unroll
    for (int k = 0; k < 4; ++k) {
      int sb = (tid & 3) * 8 + k * 32;  // s-local element offset
      bf16x8 v = *reinterpret_cast<const bf16x8*>(&sm.Tt[dh_loc][sb]);
      *reinterpret_cast<bf16x8*>(&base[sb]) = v;
    }
  }
}

// ---------------------------------------------------------------------------
// Kernel 2: causal flash attention, K=V=Q. EXACT r7 version (measured 53.3us,
// 92 VGPR, reproduced r13): 512 blocks x 4 waves, 128-row q-tiles, qt-pairing
// (i,15-i), KVBLK=128 double-buffered, T14 reg prefetch, fixed-m softmax,
// pre-scaled Q, hw cvt_pk + permlane32_swap.
// ---------------------------------------------------------------------------
__global__ __launch_bounds__(256, 2) void attn_kernel(
    const ushort* __restrict__ q, const ushort* __restrict__ qT,
    float* __restrict__ out) {
  __shared__ ushort Ks[2][128][72];    // [buf][key][d]  144B stride: conflict-free
  __shared__ ushort VTs[2][64][136];   // [buf][d][key]  272B stride: conflict-free
  const int tid = threadIdx.x, wid = tid >> 6, lane = tid & 63;
  const int l31 = lane & 31, h = lane >> 5;
  const int bid = blockIdx.x;
  const int pi = bid >> 6, bh = bid & 63;
  const int qtA = pi, qtB = 15 - pi;   // 128-row q tiles
  const int ntA = pi + 1;              // 128-key tiles for item A
  const int T = 17;                    // ntA + ntB == 17 for every block
  const ushort* Q = q + bh * (2048 * 64);
  const ushort* VT = qT + bh * (64 * 2048);
  float* O = out + (bh >> 4) * (2048 * 1024) + (bh & 15) * 64;

  int qw = qtA * 128 + wid * 32;
  int qglob = qw + l31;

  const int krow = tid >> 3, kc8 = (tid & 7) * 8;    // K: 4 rows/thread (+32)
  const int vrow = tid >> 4, vc8 = (tid & 15) * 8;   // VT: 4 rows/thread (+16)

  const float sc = 0.03125f * 1.44269504f;  // 1/sqrt(1024) * log2(e)

  bf16x8 qb[4];
#pragma unroll
  for (int ds = 0; ds < 4; ++ds)
    qb[ds] = scale8(*reinterpret_cast<const bf16x8*>(&Q[qglob * 64 + ds * 16 + h * 8]), sc);

  f32x16 o0 = {}, o1 = {};             // O^T[d][q]
  float l_run = 0.f;

  auto store_out = [&]() {
    float lt = l_run + __shfl_xor(l_run, 32);
    float inv = 1.0f / lt;
#pragma unroll
    for (int rq = 0; rq < 4; ++rq) {
      float4 v0, v1;
      v0.x = o0[4 * rq + 0] * inv; v0.y = o0[4 * rq + 1] * inv;
      v0.z = o0[4 * rq + 2] * inv; v0.w = o0[4 * rq + 3] * inv;
      v1.x = o1[4 * rq + 0] * inv; v1.y = o1[4 * rq + 1] * inv;
      v1.z = o1[4 * rq + 2] * inv; v1.w = o1[4 * rq + 3] * inv;
      *reinterpret_cast<float4*>(&O[qglob * 1024 + 8 * rq + 4 * h]) = v0;
      *reinterpret_cast<float4*>(&O[qglob * 1024 + 32 + 8 * rq + 4 * h]) = v1;
    }
  };

  bf16x8 kr[4], vr[4];
  // prologue: stage tile kv=0 into buffer 0
#pragma unroll
  for (int i = 0; i < 4; ++i) {
    kr[i] = *reinterpret_cast<const bf16x8*>(&Q[(krow + 32 * i) * 64 + kc8]);
    vr[i] = *reinterpret_cast<const bf16x8*>(&VT[(vrow + 16 * i) * 2048 + vc8]);
    *reinterpret_cast<bf16x8*>(&Ks[0][krow + 32 * i][kc8]) = kr[i];
    *reinterpret_cast<bf16x8*>(&VTs[0][vrow + 16 * i][vc8]) = vr[i];
  }
  __syncthreads();

  for (int t = 0; t < T; ++t) {
    const int p = t & 1;
    const bool more = (t + 1 < T);

    if (t == ntA) {  // item switch: finish A, start B
      store_out();
      o0 = {}; o1 = {};
      l_run = 0.f;
      qw = qtB * 128 + wid * 32;
      qglob = qw + l31;
#pragma unroll
      for (int ds = 0; ds < 4; ++ds)
        qb[ds] = scale8(*reinterpret_cast<const bf16x8*>(&Q[qglob * 64 + ds * 16 + h * 8]), sc);
    }
    const int kv0 = (t < ntA) ? t * 128 : (t - ntA) * 128;
    const bool diag = (t == ntA - 1) || (t == T - 1);  // item's last tile

    if (more) {  // issue next-tile global loads early (T14); kv wraps at ntA
      const int nkv = (t + 1 < ntA) ? (t + 1) * 128 : (t + 1 - ntA) * 128;
#pragma unroll
      for (int i = 0; i < 4; ++i) {
        kr[i] = *reinterpret_cast<const bf16x8*>(&Q[(nkv + krow + 32 * i) * 64 + kc8]);
        vr[i] = *reinterpret_cast<const bf16x8*>(&VT[(vrow + 16 * i) * 2048 + nkv + vc8]);
      }
    }

    // S^T*sc = K (Q*sc)^T: 4 chains x 4 k-steps. D: col=q=lane&31, row=key.
    f32x16 st[4] = {{}, {}, {}, {}};
    __builtin_amdgcn_s_setprio(1);
#pragma unroll
    for (int ds = 0; ds < 4; ++ds) {
#pragma unroll
      for (int c = 0; c < 4; ++c) {
        bf16x8 ka = *reinterpret_cast<const bf16x8*>(&Ks[p][32 * c + l31][ds * 16 + h * 8]);
        st[c] = MFMA32(ka, qb[ds], st[c]);
      }
    }
    __builtin_amdgcn_s_setprio(0);

    if (diag) {  // causal mask, only on the item's last tile
#pragma unroll
      for (int c = 0; c < 4; ++c)
#pragma unroll
        for (int r = 0; r < 16; ++r) {
          int key = kv0 + 32 * c + (r & 3) + 8 * (r >> 2) + 4 * h;
          if (key > qglob) st[c][r] = -1e30f;
        }
    }

    // fixed-m softmax: p = exp2(st) (scale pre-folded into Q)
    float ls = 0.f;
#pragma unroll
    for (int c = 0; c < 4; ++c)
#pragma unroll
      for (int r = 0; r < 16; ++r) {
        float pv = __builtin_amdgcn_exp2f(st[c][r]);
        st[c][r] = pv;
        ls += pv;
      }
    l_run += ls;

    // O^T += V^T P^T: 8 key-steps of 16; hw pack + 2 permlane32_swap each.
    __builtin_amdgcn_s_setprio(1);
#pragma unroll
    for (int ks = 0; ks < 8; ++ks) {
      const int cc = ks >> 1, b8 = (ks & 1) * 8;
      unsigned a0 = cvtpk(st[cc][b8 + 0], st[cc][b8 + 1]);
      unsigned a1 = cvtpk(st[cc][b8 + 2], st[cc][b8 + 3]);
      unsigned b0 = cvtpk(st[cc][b8 + 4], st[cc][b8 + 5]);
      unsigned b1 = cvtpk(st[cc][b8 + 6], st[cc][b8 + 7]);
      u32x2 r0 = __builtin_amdgcn_permlane32_swap(a0, b0, false, false);
      u32x2 r1 = __builtin_amdgcn_permlane32_swap(a1, b1, false, false);
      union { unsigned w[4]; bf16x8 v; } pb;
      pb.w[0] = r0.x; pb.w[1] = r1.x; pb.w[2] = r0.y; pb.w[3] = r1.y;
      bf16x8 va0 = *reinterpret_cast<const bf16x8*>(&VTs[p][l31][ks * 16 + h * 8]);
      bf16x8 va1 = *reinterpret_cast<const bf16x8*>(&VTs[p][32 + l31][ks * 16 + h * 8]);
      o0 = MFMA32(va0, pb.v, o0);
      o1 = MFMA32(va1, pb.v, o1);
    }
    __builtin_amdgcn_s_setprio(0);

    if (more) {  // write next tile into the other buffer
#pragma unroll
      for (int i = 0; i < 4; ++i) {
        *reinterpret_cast<bf16x8*>(&Ks[p ^ 1][krow + 32 * i][kc8]) = kr[i];
        *reinterpret_cast<bf16x8*>(&VTs[p ^ 1][vrow + 16 * i][vc8]) = vr[i];
      }
      __syncthreads();
    }
  }

  store_out();  // item B epilogue
}

extern "C" void kernel_launch(void* const* d_in, const int* in_sizes, int n_in,
                              void* d_out, int out_size, void* d_ws, size_t ws_size,
                              hipStream_t stream) {
  const float* x = (const float*)d_in[0];
  const float* w = (const float*)d_in[1];
  float* out = (float*)d_out;
  ushort* qb = (ushort*)d_ws;
  ushort* qTb = qb + 4 * 16 * 2048 * 64;
  qproj_kernel<<<dim3(64, 8), 256, 0, stream>>>(x, w, qb, qTb);
  attn_kernel<<<512, 256, 0, stream>>>(qb, qTb, out);
}

// Round 15
// 83.670 us; speedup vs baseline: 1.2748x; 1.0003x over previous
//
#include <hip/hip_runtime.h>
#include <hip/hip_bf16.h>

// MultiHeadAttention: B=4,S=2048,E=1024,H=16,D=64. Q=K=V=x@Wq^T (quirk),
// causal, scale 1/32 (sqrt(OUT_DIM) quirk). fp32 in/out, bf16 MFMA compute.
// ws: [0,16MiB) q bf16 [B,H,S,D]; [16MiB,32MiB) qT bf16 [B,H,D,S].
// r15 = qproj r11/r14 (unchanged) + attn SPLIT-KV:
//   16-wave blocks (8 row-groups x 2 key-splits), 256-row q-tiles, pairing
//   (i,7-i) -> 256 uniform blocks x 18 tiles, 1 block/CU, 4 waves/SIMD (2x).
//   fixed-m softmax makes the split merge purely additive (O+=O', l+=l').

using bf16 = __hip_bfloat16;
typedef __attribute__((ext_vector_type(8))) short bf16x8;
typedef __attribute__((ext_vector_type(4))) float f32x4;
typedef __attribute__((ext_vector_type(16))) float f32x16;
typedef __attribute__((ext_vector_type(2))) unsigned int u32x2;

#define MFMA16(a, b, c) __builtin_amdgcn_mfma_f32_16x16x32_bf16((a), (b), (c), 0, 0, 0)
#define MFMA32(a, b, c) __builtin_amdgcn_mfma_f32_32x32x16_bf16((a), (b), (c), 0, 0, 0)

// hardware packed f32x2 -> bf16x2 (RNE), T12 recipe
static __device__ __forceinline__ unsigned cvtpk(float lo, float hi) {
  unsigned r;
  asm("v_cvt_pk_bf16_f32 %0, %1, %2" : "=v"(r) : "v"(lo), "v"(hi));
  return r;
}
// scale a bf16x8 fragment by s (unpack, mul, repack)
static __device__ __forceinline__ bf16x8 scale8(bf16x8 f, float s) {
  union { bf16x8 v; unsigned w[4]; } u, r;
  u.v = f;
#pragma unroll
  for (int i = 0; i < 4; ++i) {
    float lo = __uint_as_float(u.w[i] << 16) * s;
    float hi = __uint_as_float(u.w[i] & 0xffff0000u) * s;
    r.w[i] = cvtpk(lo, hi);
  }
  return r.v;
}

// ---------------------------------------------------------------------------
// Kernel 1: q = x @ Wq^T (M=8192,N=1024,K=1024). 128x128 tile, 4 waves, BK=64
// (r11, measured ~29us): depth-1 reg prefetch, hw cvtpk staging, one barrier
// per K-slab, LDS-transpose epilogue for coalesced qT stores.
// ---------------------------------------------------------------------------
__global__ __launch_bounds__(256, 2) void qproj_kernel(
    const float* __restrict__ x, const float* __restrict__ w,
    ushort* __restrict__ q, ushort* __restrict__ qT) {
  __shared__ union {
    struct { ushort As[2][128][72]; ushort Bs[2][128][72]; } ab;  // 73.7KB
    ushort Tt[128][138];  // [dh-local][s-local] transpose tile, 276B stride
  } sm;
  const int tid = threadIdx.x;
  const int wid = tid >> 6, lane = tid & 63;
  const int l16 = lane & 15, lhi = lane >> 4;
  const int wrow = wid >> 1, wcol = wid & 1;
  const int m0 = blockIdx.x * 128, n0 = blockIdx.y * 128;

  const int srow = tid >> 4, scol = (tid & 15) * 4;

  f32x4 acc[4][4] = {};
  float4 xa[8], wb[8];

#pragma unroll
  for (int i = 0; i < 8; ++i) {
    xa[i] = *reinterpret_cast<const float4*>(&x[(m0 + srow + 16 * i) * 1024 + scol]);
    wb[i] = *reinterpret_cast<const float4*>(&w[(n0 + srow + 16 * i) * 1024 + scol]);
  }
#pragma unroll
  for (int i = 0; i < 8; ++i) {
    uint2 pa = {cvtpk(xa[i].x, xa[i].y), cvtpk(xa[i].z, xa[i].w)};
    uint2 pb = {cvtpk(wb[i].x, wb[i].y), cvtpk(wb[i].z, wb[i].w)};
    *reinterpret_cast<uint2*>(&sm.ab.As[0][srow + 16 * i][scol]) = pa;
    *reinterpret_cast<uint2*>(&sm.ab.Bs[0][srow + 16 * i][scol]) = pb;
  }
  __syncthreads();

  for (int k0 = 0; k0 < 1024; k0 += 64) {
    const int p = (k0 >> 6) & 1;
    const bool more = (k0 + 64 < 1024);
    if (more) {
#pragma unroll
      for (int i = 0; i < 8; ++i) {
        xa[i] = *reinterpret_cast<const float4*>(&x[(m0 + srow + 16 * i) * 1024 + k0 + 64 + scol]);
        wb[i] = *reinterpret_cast<const float4*>(&w[(n0 + srow + 16 * i) * 1024 + k0 + 64 + scol]);
      }
    }

    __builtin_amdgcn_s_setprio(1);
#pragma unroll
    for (int kk = 0; kk < 64; kk += 32) {
      bf16x8 af[4], bfr[4];
#pragma unroll
      for (int mr = 0; mr < 4; ++mr)
        af[mr] = *reinterpret_cast<const bf16x8*>(&sm.ab.As[p][wrow * 64 + mr * 16 + l16][kk + lhi * 8]);
#pragma unroll
      for (int nr = 0; nr < 4; ++nr)
        bfr[nr] = *reinterpret_cast<const bf16x8*>(&sm.ab.Bs[p][wcol * 64 + nr * 16 + l16][kk + lhi * 8]);
#pragma unroll
      for (int mr = 0; mr < 4; ++mr)
#pragma unroll
        for (int nr = 0; nr < 4; ++nr)
          acc[mr][nr] = MFMA16(af[mr], bfr[nr], acc[mr][nr]);
    }
    __builtin_amdgcn_s_setprio(0);

    if (more) {
#pragma unroll
      for (int i = 0; i < 8; ++i) {
        uint2 pa = {cvtpk(xa[i].x, xa[i].y), cvtpk(xa[i].z, xa[i].w)};
        uint2 pb = {cvtpk(wb[i].x, wb[i].y), cvtpk(wb[i].z, wb[i].w)};
        *reinterpret_cast<uint2*>(&sm.ab.As[p ^ 1][srow + 16 * i][scol]) = pa;
        *reinterpret_cast<uint2*>(&sm.ab.Bs[p ^ 1][srow + 16 * i][scol]) = pb;
      }
      __syncthreads();
    }
  }

  __syncthreads();  // As/Bs dead; reuse LDS as transpose tile

#pragma unroll
  for (int mr = 0; mr < 4; ++mr)
#pragma unroll
    for (int nr = 0; nr < 4; ++nr) {
      unsigned w01 = cvtpk(acc[mr][nr][0], acc[mr][nr][1]);
      unsigned w23 = cvtpk(acc[mr][nr][2], acc[mr][nr][3]);
      int rloc = wrow * 64 + mr * 16 + lhi * 4;
      int cloc = wcol * 64 + nr * 16 + l16;
      int gr = m0 + rloc, gc = n0 + cloc;
      int bb = gr >> 11, hh = gc >> 6, dh = gc & 63;
      ushort* qp = &q[(((bb * 16 + hh) * 2048) + (gr & 2047)) * 64 + dh];
      qp[0] = (ushort)(w01 & 0xffffu);
      qp[64] = (ushort)(w01 >> 16);
      qp[128] = (ushort)(w23 & 0xffffu);
      qp[192] = (ushort)(w23 >> 16);
      *reinterpret_cast<unsigned*>(&sm.Tt[cloc][rloc]) = w01;
      *reinterpret_cast<unsigned*>(&sm.Tt[cloc][rloc + 2]) = w23;
    }
  __syncthreads();

  const int bb = m0 >> 11, sl = m0 & 2047;
#pragma unroll
  for (int pp = 0; pp < 2; ++pp) {
    int dh_loc = (tid >> 2) + pp * 64;
    int gc = n0 + dh_loc;
    int hh = gc >> 6, dh = gc & 63;
    ushort* base = &qT[(((bb * 16 + hh) * 64) + dh) * 2048 + sl];
#pragma unroll
    for (int k = 0; k < 4; ++k) {
      int sb = (tid & 3) * 8 + k * 32;
      bf16x8 v = *reinterpret_cast<const bf16x8*>(&sm.Tt[dh_loc][sb]);
      *reinterpret_cast<bf16x8*>(&base[sb]) = v;
    }
  }
}

// ---------------------------------------------------------------------------
// Kernel 2: causal flash attention, K=V=Q, SPLIT-KV (r15).
// 256 blocks x 1024 threads (16 waves = 8 row-groups g x 2 key-splits s).
// 256-row q-tiles, pairing (i,7-i) -> 18 KV-tiles (KVBLK=128) per block,
// uniform. Wave (g,s) computes rows [qw,qw+32) x keys [kv0+64s, kv0+64s+64).
// fixed-m softmax => partials merge additively at item end via LDS scratch.
// Per-tile per-wave: 8 QK MFMA32 + 32 exp2 + 8 PV MFMA32 (half of r7).
// ---------------------------------------------------------------------------
__global__ __launch_bounds__(1024, 4) void attn_kernel(
    const ushort* __restrict__ q, const ushort* __restrict__ qT,
    float* __restrict__ out) {
  __shared__ ushort Ks[2][128][72];    // 36.9KB  [buf][key][d], conflict-free
  __shared__ ushort VTs[2][64][136];   // 34.8KB  [buf][d][key], conflict-free
  __shared__ f32x4 so_scr[8][2][8][32];  // 64KB  [g][h][rq(0-3:o0,4-7:o1)][l31]
  __shared__ float sl_scr[8][32];        // 1KB   split-1 l partials
  const int tid = threadIdx.x, wid = tid >> 6, lane = tid & 63;
  const int l31 = lane & 31, h = lane >> 5;
  const int g = wid >> 1, s = wid & 1;
  const int bid = blockIdx.x;
  const int pi = bid >> 6, bh = bid & 63;
  const int qtA = pi, qtB = 7 - pi;    // 256-row q tiles
  const int ntA = 2 * pi + 2;          // 128-key tiles for item A
  const int T = 18;                    // ntA + ntB == 18 for every block
  const ushort* Q = q + bh * (2048 * 64);
  const ushort* VT = qT + bh * (64 * 2048);
  float* O = out + (bh >> 4) * (2048 * 1024) + (bh & 15) * 64;

  int qw = qtA * 256 + g * 32;
  int qglob = qw + l31;

  // staging: 1024 threads, 1 chunk each. K 128x64 (16KB), VT 64x128 (16KB).
  const int krow = tid >> 3, kc8 = (tid & 7) * 8;    // 0..127
  const int vrow = tid >> 4, vc8 = (tid & 15) * 8;   // 0..63

  const float sc = 0.03125f * 1.44269504f;  // 1/sqrt(1024) * log2(e)

  bf16x8 qb[4];
#pragma unroll
  for (int ds = 0; ds < 4; ++ds)
    qb[ds] = scale8(*reinterpret_cast<const bf16x8*>(&Q[qglob * 64 + ds * 16 + h * 8]), sc);

  f32x16 o0 = {}, o1 = {};             // O^T partial (this wave's key split)
  float l_run = 0.f;

  // merge split partials (additive thanks to fixed-m) and store the item.
  auto merge_store = [&]() {
    float lt = l_run + __shfl_xor(l_run, 32);  // combine h halves (per wave)
    if (s == 1) {
#pragma unroll
      for (int rq = 0; rq < 4; ++rq) {
        f32x4 t0, t1;
        t0[0] = o0[4 * rq + 0]; t0[1] = o0[4 * rq + 1];
        t0[2] = o0[4 * rq + 2]; t0[3] = o0[4 * rq + 3];
        t1[0] = o1[4 * rq + 0]; t1[1] = o1[4 * rq + 1];
        t1[2] = o1[4 * rq + 2]; t1[3] = o1[4 * rq + 3];
        so_scr[g][h][rq][l31] = t0;
        so_scr[g][h][rq + 4][l31] = t1;
      }
      if (h == 0) sl_scr[g][l31] = lt;
    }
    __syncthreads();
    if (s == 0) {
      float inv = 1.0f / (lt + sl_scr[g][l31]);
#pragma unroll
      for (int rq = 0; rq < 4; ++rq) {
        f32x4 a0 = so_scr[g][h][rq][l31];
        f32x4 a1 = so_scr[g][h][rq + 4][l31];
        float4 v0, v1;
        v0.x = (o0[4 * rq + 0] + a0[0]) * inv; v0.y = (o0[4 * rq + 1] + a0[1]) * inv;
        v0.z = (o0[4 * rq + 2] + a0[2]) * inv; v0.w = (o0[4 * rq + 3] + a0[3]) * inv;
        v1.x = (o1[4 * rq + 0] + a1[0]) * inv; v1.y = (o1[4 * rq + 1] + a1[1]) * inv;
        v1.z = (o1[4 * rq + 2] + a1[2]) * inv; v1.w = (o1[4 * rq + 3] + a1[3]) * inv;
        *reinterpret_cast<float4*>(&O[qglob * 1024 + 8 * rq + 4 * h]) = v0;
        *reinterpret_cast<float4*>(&O[qglob * 1024 + 32 + 8 * rq + 4 * h]) = v1;
      }
    }
  };

  bf16x8 kr, vr;
  // prologue: stage tile kv=0 into buffer 0
  kr = *reinterpret_cast<const bf16x8*>(&Q[krow * 64 + kc8]);
  vr = *reinterpret_cast<const bf16x8*>(&VT[vrow * 2048 + vc8]);
  *reinterpret_cast<bf16x8*>(&Ks[0][krow][kc8]) = kr;
  *reinterpret_cast<bf16x8*>(&VTs[0][vrow][vc8]) = vr;
  __syncthreads();

  for (int t = 0; t < T; ++t) {
    const int p = t & 1;
    const bool more = (t + 1 < T);

    if (t == ntA) {  // item switch: merge+store A, reset for B
      merge_store();
      o0 = {}; o1 = {};
      l_run = 0.f;
      qw = qtB * 256 + g * 32;
      qglob = qw + l31;
#pragma unroll
      for (int ds = 0; ds < 4; ++ds)
        qb[ds] = scale8(*reinterpret_cast<const bf16x8*>(&Q[qglob * 64 + ds * 16 + h * 8]), sc);
    }
    const int kv0 = (t < ntA) ? t * 128 : (t - ntA) * 128;
    const int kvs = kv0 + s * 64;                 // this wave's key window
    const bool skip = (kvs > qw + 31);            // entirely above diagonal
    const bool mask = !skip && (kvs + 63 > qw);   // diagonal band

    if (more) {  // issue next-tile global loads early (T14); kv wraps at ntA
      const int nkv = (t + 1 < ntA) ? (t + 1) * 128 : (t + 1 - ntA) * 128;
      kr = *reinterpret_cast<const bf16x8*>(&Q[(nkv + krow) * 64 + kc8]);
      vr = *reinterpret_cast<const bf16x8*>(&VT[vrow * 2048 + nkv + vc8]);
    }

    if (!skip) {
      // S^T*sc = K (Q*sc)^T over 64 keys: 2 chains x 4 k-steps.
      f32x16 st[2] = {{}, {}};
      __builtin_amdgcn_s_setprio(1);
#pragma unroll
      for (int ds = 0; ds < 4; ++ds) {
#pragma unroll
        for (int c = 0; c < 2; ++c) {
          bf16x8 ka = *reinterpret_cast<const bf16x8*>(&Ks[p][kvs - kv0 + 32 * c + l31][ds * 16 + h * 8]);
          st[c] = MFMA32(ka, qb[ds], st[c]);
        }
      }
      __builtin_amdgcn_s_setprio(0);

      if (mask) {
#pragma unroll
        for (int c = 0; c < 2; ++c)
#pragma unroll
          for (int r = 0; r < 16; ++r) {
            int key = kvs + 32 * c + (r & 3) + 8 * (r >> 2) + 4 * h;
            if (key > qglob) st[c][r] = -1e30f;
          }
      }

      // fixed-m softmax: p = exp2(st) (scale pre-folded into Q)
      float ls = 0.f;
#pragma unroll
      for (int c = 0; c < 2; ++c)
#pragma unroll
        for (int r = 0; r < 16; ++r) {
          float pv = __builtin_amdgcn_exp2f(st[c][r]);
          st[c][r] = pv;
          ls += pv;
        }
      l_run += ls;

      // O^T += V^T P^T over this split: 4 key-steps of 16.
      __builtin_amdgcn_s_setprio(1);
#pragma unroll
      for (int ks = 0; ks < 4; ++ks) {
        const int cc = ks >> 1, b8 = (ks & 1) * 8;
        unsigned a0 = cvtpk(st[cc][b8 + 0], st[cc][b8 + 1]);
        unsigned a1 = cvtpk(st[cc][b8 + 2], st[cc][b8 + 3]);
        unsigned b0 = cvtpk(st[cc][b8 + 4], st[cc][b8 + 5]);
        unsigned b1 = cvtpk(st[cc][b8 + 6], st[cc][b8 + 7]);
        u32x2 r0 = __builtin_amdgcn_permlane32_swap(a0, b0, false, false);
        u32x2 r1 = __builtin_amdgcn_permlane32_swap(a1, b1, false, false);
        union { unsigned w[4]; bf16x8 v; } pb;
        pb.w[0] = r0.x; pb.w[1] = r1.x; pb.w[2] = r0.y; pb.w[3] = r1.y;
        const int kc = (kvs - kv0) + ks * 16 + h * 8;
        bf16x8 va0 = *reinterpret_cast<const bf16x8*>(&VTs[p][l31][kc]);
        bf16x8 va1 = *reinterpret_cast<const bf16x8*>(&VTs[p][32 + l31][kc]);
        o0 = MFMA32(va0, pb.v, o0);
        o1 = MFMA32(va1, pb.v, o1);
      }
      __builtin_amdgcn_s_setprio(0);
    }

    if (more) {  // write next tile into the other buffer
      *reinterpret_cast<bf16x8*>(&Ks[p ^ 1][krow][kc8]) = kr;
      *reinterpret_cast<bf16x8*>(&VTs[p ^ 1][vrow][vc8]) = vr;
      __syncthreads();
    }
  }

  merge_store();  // item B
}

extern "C" void kernel_launch(void* const* d_in, const int* in_sizes, int n_in,
                              void* d_out, int out_size, void* d_ws, size_t ws_size,
                              hipStream_t stream) {
  const float* x = (const float*)d_in[0];
  const float* w = (const float*)d_in[1];
  float* out = (float*)d_out;
  ushort* qb = (ushort*)d_ws;
  ushort* qTb = qb + 4 * 16 * 2048 * 64;
  qproj_kernel<<<dim3(64, 8), 256, 0, stream>>>(x, w, qb, qTb);
  attn_kernel<<<256, 1024, 0, stream>>>(qb, qTb, out);
}